// Round 14
// baseline (146.546 us; speedup 1.0000x reference)
//
#include <hip/hip_runtime.h>
#include <hip/hip_bf16.h>

typedef __attribute__((ext_vector_type(8))) short short8;
typedef __attribute__((ext_vector_type(4))) float f32x4;

#define TEMP_INV 20.0f
#define NCH 1028

__device__ inline unsigned short f2bf(float f){
    unsigned int u = __builtin_bit_cast(unsigned int, f);
    u += 0x7fffu + ((u >> 16) & 1u);
    return (unsigned short)(u >> 16);
}
__device__ inline unsigned int pk2bf(float a, float b){
    return (unsigned int)f2bf(a) | ((unsigned int)f2bf(b) << 16);
}
__device__ inline short8 pack8(float4 a, float4 b){
    union { unsigned int u[4]; short8 s; } P;
    P.u[0] = pk2bf(a.x, a.y); P.u[1] = pk2bf(a.z, a.w);
    P.u[2] = pk2bf(b.x, b.y); P.u[3] = pk2bf(b.z, b.w);
    return P.s;
}

// ---------------------------------------------------------------------------
// k_norm: normalize query rows -> bf16 A2 in FRAGMENT-MAJOR layout:
// A2[((kc*2+ks)*16+fm)*512 + lane*8 + e], lane = fg*16+frow, so k_main's
// per-(kc,ks,fm) A-fragment load is one fully-coalesced 1KB wave-load at
// base + lane*16B. Zeroes out[0] (k_lse atomicAdds into it).
// ---------------------------------------------------------------------------
__global__ __launch_bounds__(256) void k_norm(const float* __restrict__ q,
                                              unsigned short* __restrict__ A2,
                                              float* __restrict__ out){
    int b = blockIdx.x, t = threadIdx.x;
    if (b == 0 && t == 0) out[0] = 0.f;
    const float* qr = q + b * 768;
    float v0 = qr[t], v1 = qr[t + 256], v2 = qr[t + 512];
    float ss = v0*v0 + v1*v1 + v2*v2;
#pragma unroll
    for (int o = 32; o; o >>= 1) ss += __shfl_xor(ss, o);
    __shared__ float red[4];
    if ((t & 63) == 0) red[t >> 6] = ss;
    __syncthreads();
    ss = red[0] + red[1] + red[2] + red[3];
    float inv = 1.0f / fmaxf(sqrtf(ss), 1e-8f);
    float nv[3] = {v0 * inv, v1 * inv, v2 * inv};
    const int fm = b >> 4, frow = b & 15;
#pragma unroll
    for (int j = 0; j < 3; j++){
        int cc = t + 256 * j;
        int kc = cc >> 6, kw = cc & 63;
        int ks = kw >> 5, k32 = kw & 31, fg = k32 >> 3, e = k32 & 7;
        int lane = fg * 16 + frow;
        A2[((kc * 2 + ks) * 16 + fm) * 512 + lane * 8 + e] = f2bf(nv[j]);
    }
}

// ---------------------------------------------------------------------------
// k_main: BARRIER-FREE K-loop. 1028 blocks x 256 thr = 4112 independent
// waves; wave wid owns combined cols [16*wid, 16*wid+16) (wid<16: keys ->
// sim_pos + diag; else queue rows wid*16-256...). Wave tile = 256 rows x 16
// cols, acc[16] = 64 AGPR. Per kc: each lane loads ITS OWN 64B of f32 B
// (col=frow, k=fg*8 slots), converts in-register (B-frag layout is lane-
// local!), and A-frags stream as coalesced 1KB wave-loads from the L1/L2-hot
// fragment-major A2 (0.4 MB). No LDS, no __syncthreads until the 4-wave
// epilogue merge. ssq per col is lane-local -> shfl_xor(16,32) over the fg
// group. kc loop ROLLED (R9: full unroll => 109 MB spill).
// ---------------------------------------------------------------------------
__global__ __launch_bounds__(256) void k_main(
        const float* __restrict__ keys,
        const float* __restrict__ queue,
        const unsigned short* __restrict__ A2,
        float* __restrict__ pmax,
        float* __restrict__ psum,
        float* __restrict__ diag){
    __shared__ float redm[4][256];
    __shared__ float reds[4][256];

    const int b = blockIdx.x, t = threadIdx.x;
    const int lane = t & 63, w = t >> 6;
    const int wid = b * 4 + w;
    const int frow = lane & 15, fg = lane >> 4;
    const int colglob = wid * 16 + frow;          // 0..65791
    const bool keyw = (wid < 16);
    const float* src = keyw ? (keys + colglob * 768)
                            : (queue + (size_t)(colglob - 256) * 768);
    const float* rp = src + fg * 8;

    float ssq = 0.f;
    f32x4 acc[16];
#pragma unroll
    for (int i = 0; i < 16; i++) acc[i] = (f32x4)0.f;

#pragma unroll 1
    for (int kc = 0; kc < 12; ++kc){
        // B: this lane's own 64 B (f32) for k-slots fg*8 of both 32-slices
        float4 u0 = *(const float4*)(rp + kc * 64);
        float4 u1 = *(const float4*)(rp + kc * 64 + 4);
        float4 u2 = *(const float4*)(rp + kc * 64 + 32);
        float4 u3 = *(const float4*)(rp + kc * 64 + 36);
        ssq += u0.x*u0.x + u0.y*u0.y + u0.z*u0.z + u0.w*u0.w;
        ssq += u1.x*u1.x + u1.y*u1.y + u1.z*u1.z + u1.w*u1.w;
        ssq += u2.x*u2.x + u2.y*u2.y + u2.z*u2.z + u2.w*u2.w;
        ssq += u3.x*u3.x + u3.y*u3.y + u3.z*u3.z + u3.w*u3.w;
        short8 bf0 = pack8(u0, u1);
        short8 bf1 = pack8(u2, u3);
        // A-frags: coalesced 1KB wave-loads from fragment-major A2
        const unsigned short* a0 = A2 + (kc * 2 + 0) * 16 * 512 + lane * 8;
        const unsigned short* a1 = A2 + (kc * 2 + 1) * 16 * 512 + lane * 8;
#pragma unroll
        for (int fm = 0; fm < 16; ++fm){
            short8 af = *(const short8*)(a0 + fm * 512);
            acc[fm] = __builtin_amdgcn_mfma_f32_16x16x32_bf16(af, bf0, acc[fm], 0, 0, 0);
        }
#pragma unroll
        for (int fm = 0; fm < 16; ++fm){
            short8 af = *(const short8*)(a1 + fm * 512);
            acc[fm] = __builtin_amdgcn_mfma_f32_16x16x32_bf16(af, bf1, acc[fm], 0, 0, 0);
        }
    }

    // column norm: fg-group holds the 4 quarters of col frow
    ssq += __shfl_xor(ssq, 16);
    ssq += __shfl_xor(ssq, 32);
    const float scale = TEMP_INV / fmaxf(sqrtf(ssq), 1e-8f);

    // scale, diag, per-row (max,sumexp) over this wave's 16 cols
#pragma unroll
    for (int fm = 0; fm < 16; ++fm){
#pragma unroll
        for (int rr = 0; rr < 4; ++rr){
            float v = acc[fm][rr] * scale;
            int row = fm * 16 + fg * 4 + rr;
            if (keyw && row == colglob) diag[row] = v;
            float m = v;
#pragma unroll
            for (int o = 1; o < 16; o <<= 1) m = fmaxf(m, __shfl_xor(m, o));
            float e = __expf(v - m);
#pragma unroll
            for (int o = 1; o < 16; o <<= 1) e += __shfl_xor(e, o);
            if (frow == 0){ redm[w][row] = m; reds[w][row] = e; }
        }
    }
    __syncthreads();
    if (t < 256){
        float M = -1e30f, S = 0.f;
#pragma unroll
        for (int ww = 0; ww < 4; ++ww){
            float m2 = redm[ww][t], s2 = reds[ww][t];
            float Mn = fmaxf(M, m2);
            S = S * __expf(M - Mn) + s2 * __expf(m2 - Mn);
            M = Mn;
        }
        pmax[b * 256 + t] = M;
        psum[b * 256 + t] = S;
    }
}

// ---------------------------------------------------------------------------
// k_lse: per q-row, merge 1028 chunk partials; atomicAdd loss contribution.
// ---------------------------------------------------------------------------
__global__ __launch_bounds__(256) void k_lse(const float* __restrict__ pmax,
                                             const float* __restrict__ psum,
                                             const float* __restrict__ diag,
                                             float* __restrict__ out){
    int b = blockIdx.x, t = threadIdx.x;
    float m = -1e30f;
    for (int cc = t; cc < NCH; cc += 256) m = fmaxf(m, pmax[cc * 256 + b]);
#pragma unroll
    for (int o = 32; o; o >>= 1) m = fmaxf(m, __shfl_xor(m, o));
    __shared__ float red[4];
    __shared__ float Msh;
    if ((t & 63) == 0) red[t >> 6] = m;
    __syncthreads();
    if (t == 0) Msh = fmaxf(fmaxf(red[0], red[1]), fmaxf(red[2], red[3]));
    __syncthreads();
    float M = Msh;
    float s = 0.f;
    for (int cc = t; cc < NCH; cc += 256) s += psum[cc * 256 + b] * __expf(pmax[cc * 256 + b] - M);
#pragma unroll
    for (int o = 32; o; o >>= 1) s += __shfl_xor(s, o);
    if ((t & 63) == 0) red[t >> 6] = s;
    __syncthreads();
    if (t == 0)
        atomicAdd(out, (M + logf(red[0] + red[1] + red[2] + red[3]) - diag[b]) * (1.0f / 256.0f));
}

extern "C" void kernel_launch(void* const* d_in, const int* in_sizes, int n_in,
                              void* d_out, int out_size, void* d_ws, size_t ws_size,
                              hipStream_t stream){
    const float* q  = (const float*)d_in[0];
    const float* k  = (const float*)d_in[1];
    const float* qu = (const float*)d_in[2];
    char* ws = (char*)d_ws;
    // ws layout (bytes): A2 0..393216 | diag ..394240 |
    //                    pmax ..1446912 | psum ..2499584
    unsigned short* A2 = (unsigned short*)(ws);
    float* diag  = (float*)(ws + 393216);
    float* pmax  = (float*)(ws + 394240);
    float* psum  = (float*)(ws + 1446912);

    k_norm<<<256, 256, 0, stream>>>(q, A2, (float*)d_out);
    k_main<<<1028, 256, 0, stream>>>(k, qu, A2, pmax, psum, diag);
    k_lse<<<256, 256, 0, stream>>>(pmax, psum, diag, (float*)d_out);
}

// Round 15
// 120.535 us; speedup vs baseline: 1.2158x; 1.2158x over previous
//
#include <hip/hip_runtime.h>
#include <hip/hip_bf16.h>

typedef __attribute__((ext_vector_type(8))) short short8;
typedef __attribute__((ext_vector_type(4))) float f32x4;

#define TEMP_INV 20.0f
#define NCH 1028

__device__ inline unsigned short f2bf(float f){
    unsigned int u = __builtin_bit_cast(unsigned int, f);
    u += 0x7fffu + ((u >> 16) & 1u);
    return (unsigned short)(u >> 16);
}
__device__ inline unsigned int pk2bf(float a, float b){
    return (unsigned int)f2bf(a) | ((unsigned int)f2bf(b) << 16);
}
__device__ inline short8 pack8(float4 a, float4 b){
    union { unsigned int u[4]; short8 s; } P;
    P.u[0] = pk2bf(a.x, a.y); P.u[1] = pk2bf(a.z, a.w);
    P.u[2] = pk2bf(b.x, b.y); P.u[3] = pk2bf(b.z, b.w);
    return P.s;
}

#define GLOAD16(src, dst) __builtin_amdgcn_global_load_lds( \
    (const __attribute__((address_space(1))) unsigned int*)(src), \
    (__attribute__((address_space(3))) unsigned int*)(dst), 16, 0, 0)

// ---------------------------------------------------------------------------
// k_norm: normalize query rows -> bf16 A, pre-swizzled [12][256][64]
// (slot = g ^ (row&7)) for linear global_load_lds staging. Zeroes out[0].
// ---------------------------------------------------------------------------
__global__ __launch_bounds__(256) void k_norm(const float* __restrict__ q,
                                              unsigned short* __restrict__ Aswz,
                                              float* __restrict__ out){
    int b = blockIdx.x, t = threadIdx.x;
    if (b == 0 && t == 0) out[0] = 0.f;
    const float* qr = q + b * 768;
    float v0 = qr[t], v1 = qr[t + 256], v2 = qr[t + 512];
    float ss = v0*v0 + v1*v1 + v2*v2;
#pragma unroll
    for (int o = 32; o; o >>= 1) ss += __shfl_xor(ss, o);
    __shared__ float red[4];
    if ((t & 63) == 0) red[t >> 6] = ss;
    __syncthreads();
    ss = red[0] + red[1] + red[2] + red[3];
    float inv = 1.0f / fmaxf(sqrtf(ss), 1e-8f);
    float nv[3] = {v0 * inv, v1 * inv, v2 * inv};
#pragma unroll
    for (int j = 0; j < 3; j++){
        int cc = t + 256 * j;
        unsigned short hh = f2bf(nv[j]);
        int kc = cc >> 6, kl = cc & 63, g = kl >> 3, e = kl & 7;
        int slot = g ^ (b & 7);
        Aswz[kc * 16384 + b * 64 + slot * 8 + e] = hh;
    }
}

// ---------------------------------------------------------------------------
// k_main: 1028 blocks x 512 thr (8 waves). Block b: cols [64b,64b+64)
// (b<1024: queue; b>=1024: keys -> sim_pos + diag). Wave (h=w>>2, cg=w&3) =
// rows [128h,+128) x cols [16cg,+16); acc[8] = 32 AGPR.
//   B: per-lane in-register (col = frow, k-slice = fg*8; 256B/col/kc
//      contiguous) -> pack8 -> MFMA B-operand directly. NO B LDS/ds_write.
//   A: [256][64] swizzled tile, 32KB DMA via global_load_lds, double-
//      buffered; shared by all 8 waves.
// Per kc: vmcnt(4) [A(kc) only -- B(kc) stays in flight across barrier] ->
// barrier -> issue A(kc+1) DMA -> pack B(kc) -> issue B(kc+1) -> 16 MFMA.
// ONE barrier/kc; vmcnt(0) never (tail only implicitly). kc ROLLED (R9:
// unroll => 109MB spill). Regs ~107 -> launch_bounds(512,4), 2 blocks/CU.
// ---------------------------------------------------------------------------
__global__ __launch_bounds__(512, 4) void k_main(
        const float* __restrict__ keys,
        const float* __restrict__ queue,
        const unsigned short* __restrict__ Aswz,
        float* __restrict__ pmax,
        float* __restrict__ psum,
        float* __restrict__ diag){
    __shared__ unsigned short Abuf[2][16384]; // 64 KB dbuf [256][64] swizzled
    __shared__ float redm[4][256];
    __shared__ float reds[4][256];

    const int b = blockIdx.x, t = threadIdx.x;
    const int lane = t & 63, w = t >> 6;
    const int h = w >> 2, cg = w & 3;
    const int frow = lane & 15, fg = lane >> 4;
    const bool keyb = (b >= 1024);
    const int colg = (keyb ? (b - 1024) : b) * 64 + cg * 16 + frow;
    const float* rp = (keyb ? keys : queue) + (size_t)colg * 768 + fg * 8;

    float ssq = 0.f;
    f32x4 acc[8];
#pragma unroll
    for (int i = 0; i < 8; i++) acc[i] = (f32x4)0.f;

    // prologue: A(0) DMA, B(0) regs
#pragma unroll
    for (int i = 0; i < 4; ++i)
        GLOAD16(Aswz + i * 4096 + t * 8, &Abuf[0][i * 4096 + t * 8]);
    float4 cu0 = *(const float4*)(rp);
    float4 cu1 = *(const float4*)(rp + 4);
    float4 cu2 = *(const float4*)(rp + 32);
    float4 cu3 = *(const float4*)(rp + 36);

#pragma unroll 1
    for (int kc = 0; kc < 12; ++kc){
        // A(kc) DMA complete for ALL waves (4 newest VMEM = B(kc) regs ok)
        asm volatile("s_waitcnt vmcnt(4)" ::: "memory");
        __builtin_amdgcn_s_barrier();
        asm volatile("" ::: "memory");

        // issue A(kc+1) DMA (safe: all waves past barrier, other buf)
        if (kc < 11){
#pragma unroll
            for (int i = 0; i < 4; ++i)
                GLOAD16(Aswz + (kc + 1) * 16384 + i * 4096 + t * 8,
                        &Abuf[(kc + 1) & 1][i * 4096 + t * 8]);
        }
        // pack B(kc) (compiler auto-waits the 4 B loads), accumulate ssq
        ssq += cu0.x*cu0.x + cu0.y*cu0.y + cu0.z*cu0.z + cu0.w*cu0.w;
        ssq += cu1.x*cu1.x + cu1.y*cu1.y + cu1.z*cu1.z + cu1.w*cu1.w;
        ssq += cu2.x*cu2.x + cu2.y*cu2.y + cu2.z*cu2.z + cu2.w*cu2.w;
        ssq += cu3.x*cu3.x + cu3.y*cu3.y + cu3.z*cu3.z + cu3.w*cu3.w;
        short8 bf0 = pack8(cu0, cu1);
        short8 bf1 = pack8(cu2, cu3);
        // issue B(kc+1) (in flight across next barrier)
        if (kc < 11){
            cu0 = *(const float4*)(rp + (kc + 1) * 64);
            cu1 = *(const float4*)(rp + (kc + 1) * 64 + 4);
            cu2 = *(const float4*)(rp + (kc + 1) * 64 + 32);
            cu3 = *(const float4*)(rp + (kc + 1) * 64 + 36);
        }
        // MFMA: A-frags from LDS (shared), B from regs
        const unsigned short* At = Abuf[kc & 1];
        const int slot0 = fg ^ (frow & 7);
        const int slot1 = (4 + fg) ^ (frow & 7);
#pragma unroll
        for (int fm = 0; fm < 8; ++fm){
            short8 af = *(const short8*)&At[(h * 128 + fm * 16 + frow) * 64 + slot0 * 8];
            acc[fm] = __builtin_amdgcn_mfma_f32_16x16x32_bf16(af, bf0, acc[fm], 0, 0, 0);
        }
#pragma unroll
        for (int fm = 0; fm < 8; ++fm){
            short8 af = *(const short8*)&At[(h * 128 + fm * 16 + frow) * 64 + slot1 * 8];
            acc[fm] = __builtin_amdgcn_mfma_f32_16x16x32_bf16(af, bf1, acc[fm], 0, 0, 0);
        }
    }

    // ---- epilogue ----
    // column norm: fg-group (lanes differing in bits 4..5) holds col slices
    ssq += __shfl_xor(ssq, 16);
    ssq += __shfl_xor(ssq, 32);
    const float scale = TEMP_INV / fmaxf(sqrtf(ssq), 1e-8f);

#pragma unroll
    for (int fm = 0; fm < 8; ++fm){
#pragma unroll
        for (int rr = 0; rr < 4; ++rr){
            float v = acc[fm][rr] * scale;
            int rloc = h * 128 + fm * 16 + fg * 4 + rr;
            if (keyb && rloc == colg) diag[rloc] = v;
            float m = v;
#pragma unroll
            for (int o = 1; o < 16; o <<= 1) m = fmaxf(m, __shfl_xor(m, o));
            float e = __expf(v - m);
#pragma unroll
            for (int o = 1; o < 16; o <<= 1) e += __shfl_xor(e, o);
            if (frow == 0){ redm[cg][rloc] = m; reds[cg][rloc] = e; }
        }
    }
    __syncthreads();
    if (t < 256){
        float M = -1e30f, S = 0.f;
#pragma unroll
        for (int g = 0; g < 4; ++g){
            float m2 = redm[g][t], s2 = reds[g][t];
            float Mn = fmaxf(M, m2);
            S = S * __expf(M - Mn) + s2 * __expf(m2 - Mn);
            M = Mn;
        }
        pmax[b * 256 + t] = M;
        psum[b * 256 + t] = S;
    }
}

// ---------------------------------------------------------------------------
// k_lse: per q-row, merge 1028 chunk partials; atomicAdd loss contribution.
// ---------------------------------------------------------------------------
__global__ __launch_bounds__(256) void k_lse(const float* __restrict__ pmax,
                                             const float* __restrict__ psum,
                                             const float* __restrict__ diag,
                                             float* __restrict__ out){
    int b = blockIdx.x, t = threadIdx.x;
    float m = -1e30f;
    for (int cc = t; cc < NCH; cc += 256) m = fmaxf(m, pmax[cc * 256 + b]);
#pragma unroll
    for (int o = 32; o; o >>= 1) m = fmaxf(m, __shfl_xor(m, o));
    __shared__ float red[4];
    __shared__ float Msh;
    if ((t & 63) == 0) red[t >> 6] = m;
    __syncthreads();
    if (t == 0) Msh = fmaxf(fmaxf(red[0], red[1]), fmaxf(red[2], red[3]));
    __syncthreads();
    float M = Msh;
    float s = 0.f;
    for (int cc = t; cc < NCH; cc += 256) s += psum[cc * 256 + b] * __expf(pmax[cc * 256 + b] - M);
#pragma unroll
    for (int o = 32; o; o >>= 1) s += __shfl_xor(s, o);
    if ((t & 63) == 0) red[t >> 6] = s;
    __syncthreads();
    if (t == 0)
        atomicAdd(out, (M + logf(red[0] + red[1] + red[2] + red[3]) - diag[b]) * (1.0f / 256.0f));
}

extern "C" void kernel_launch(void* const* d_in, const int* in_sizes, int n_in,
                              void* d_out, int out_size, void* d_ws, size_t ws_size,
                              hipStream_t stream){
    const float* q  = (const float*)d_in[0];
    const float* k  = (const float*)d_in[1];
    const float* qu = (const float*)d_in[2];
    char* ws = (char*)d_ws;
    // ws layout (bytes): Aswz 0..393216 | diag ..394240 |
    //                    pmax ..1446912 | psum ..2499584
    unsigned short* Aswz = (unsigned short*)(ws);
    float* diag  = (float*)(ws + 393216);
    float* pmax  = (float*)(ws + 394240);
    float* psum  = (float*)(ws + 1446912);

    k_norm<<<256, 256, 0, stream>>>(q, Aswz, (float*)d_out);
    k_main<<<1028, 512, 0, stream>>>(k, qu, Aswz, pmax, psum, diag);
    k_lse<<<256, 256, 0, stream>>>(pmax, psum, diag, (float*)d_out);
}